// Round 7
// baseline (441.462 us; speedup 1.0000x reference)
//
#include <hip/hip_runtime.h>
#include <hip/hip_cooperative_groups.h>
namespace cg = cooperative_groups;

#define N_NODES 100000
#define E_EDGES 1600000
#define IN_F    128
#define HID_F   64
#define OUT_F   64
#define BN_EPS  1e-5f
#define NBUK    391    // ceil(N/256) coarse buckets (256 nodes each)
#define CHUNK_C 4093   // ceil(E/391)
#define NGBLK   3125   // N/32 gather blocks (32 nodes per block, 8 lanes/node)
#define NMBLK   1563   // ceil(N/64) gemm blocks

typedef __bf16 bf16x8 __attribute__((ext_vector_type(8)));
typedef float  f32x4  __attribute__((ext_vector_type(4)));

// bf16 helpers ---------------------------------------------------------------
__device__ __forceinline__ float bflo(unsigned int u) { return __uint_as_float(u << 16); }
__device__ __forceinline__ float bfhi(unsigned int u) { return __uint_as_float(u & 0xFFFF0000u); }
__device__ __forceinline__ unsigned int pack2bf(float a, float b) {
    unsigned int ua = __float_as_uint(a), ub = __float_as_uint(b);
    ua = (ua + 0x7fffu + ((ua >> 16) & 1u)) >> 16;          // RNE
    ub = (ub + 0x7fffu + ((ub >> 16) & 1u)) >> 16;
    return ua | (ub << 16);
}
__device__ __forceinline__ unsigned short bf1(float a) {
    unsigned int ua = __float_as_uint(a);
    return (unsigned short)((ua + 0x7fffu + ((ua >> 16) & 1u)) >> 16);
}
#define ADD8(A, u)                                           \
    do {                                                     \
        A[0] += bflo((u).x); A[1] += bfhi((u).x);            \
        A[2] += bflo((u).y); A[3] += bfhi((u).y);            \
        A[4] += bflo((u).z); A[5] += bfhi((u).z);            \
        A[6] += bflo((u).w); A[7] += bfhi((u).w);            \
    } while (0)

// ---------------------------------------------------------------------------
// 1. Cooperative CSR build: zero -> coarse hist -> scan -> bucket scatter ->
//    per-bucket fine CSR + dis. One dispatch, 4 grid syncs.
__global__ __launch_bounds__(512) void k_csr(const int* __restrict__ srcv,
                                             const int* __restrict__ dstv,
                                             int* __restrict__ coff,
                                             int* __restrict__ ccur,
                                             unsigned int* __restrict__ aux,
                                             int* __restrict__ rowptr,
                                             float* __restrict__ dis,
                                             int* __restrict__ csr_src,
                                             float* __restrict__ bnstats) {
    cg::grid_group grid = cg::this_grid();
    __shared__ int dl[CHUNK_C];                    // 16372 B (also scan buffer)
    __shared__ int hA[NBUK], hB[NBUK], hC[NBUK];   // 4692 B
    const int tid = threadIdx.x;
    const int b = blockIdx.x;
    const int e0 = b * CHUNK_C;
    const int e1 = min(E_EDGES, e0 + CHUNK_C);

    // Phase 0: zero coff + bnstats (replaces host memsets)
    if (tid == 0) { coff[b] = 0; if (b == 0) coff[NBUK] = 0; }
    if (b == 1 && tid < 128) bnstats[tid] = 0.f;
    grid.sync();

    // Phase A: coarse histogram via LDS aggregation
    for (int i = tid; i < NBUK; i += 512) hA[i] = 0;
    __syncthreads();
    for (int e = e0 + tid; e < e1; e += 512)
        atomicAdd(&hA[dstv[e] >> 8], 1);
    __syncthreads();
    for (int i = tid; i < NBUK; i += 512)
        if (hA[i]) atomicAdd(&coff[i], hA[i]);
    grid.sync();

    // Phase B: exclusive scan of 391 coarse counts (block 0 only)
    if (b == 0) {
        int v = (tid < NBUK) ? coff[tid] : 0;
        dl[tid] = v;
        __syncthreads();
        for (int off = 1; off < 512; off <<= 1) {
            int t = (tid >= off) ? dl[tid - off] : 0;
            __syncthreads();
            dl[tid] += t;
            __syncthreads();
        }
        int excl = dl[tid] - v;
        if (tid < NBUK) { coff[tid] = excl; ccur[tid] = excl; }
        if (tid == 0) coff[NBUK] = E_EDGES;
    }
    grid.sync();

    // Phase C: bucket scatter aux[pos] = src<<8 | (dst&255)
    for (int i = tid; i < NBUK; i += 512) hA[i] = 0;
    __syncthreads();
    for (int e = e0 + tid; e < e1; e += 512) {
        int d = dstv[e];
        dl[e - e0] = d;
        atomicAdd(&hA[d >> 8], 1);
    }
    __syncthreads();
    for (int i = tid; i < NBUK; i += 512) {
        int h = hA[i];
        hB[i] = h ? atomicAdd(&ccur[i], h) : 0;
        hC[i] = 0;
    }
    __syncthreads();
    for (int e = e0 + tid; e < e1; e += 512) {
        int d = dl[e - e0];
        int bk = d >> 8;
        int off = atomicAdd(&hC[bk], 1);
        aux[hB[bk] + off] = ((unsigned int)srcv[e] << 8) | (unsigned int)(d & 255);
    }
    grid.sync();

    // Phase D: per-bucket fine CSR (block b = bucket b, 256 nodes)
    const int n0 = b << 8;
    const int nn = min(256, N_NODES - n0);
    const int estart = coff[b], eend = coff[b + 1];
    if (tid < 256) hA[tid] = 0;                    // c0 counts
    __syncthreads();
    for (int e = estart + tid; e < eend; e += 512)
        atomicAdd(&hA[aux[e] & 255], 1);
    __syncthreads();
    if (tid < 256) hB[tid] = hA[tid];
    __syncthreads();
    for (int off = 1; off < 256; off <<= 1) {
        int t = 0;
        if (tid < 256 && tid >= off) t = hB[tid - off];
        __syncthreads();
        if (tid < 256) hB[tid] += t;
        __syncthreads();
    }
    if (tid < 256) {
        int v = hA[tid];
        int p = estart + hB[tid] - v;              // exclusive prefix
        hC[tid] = p;                               // cursor
        if (tid < nn) {
            rowptr[n0 + tid] = p;
            dis[n0 + tid] = rsqrtf((float)v + 1.0f);
        }
    }
    if (b == NBUK - 1 && tid == 0) rowptr[N_NODES] = E_EDGES;
    __syncthreads();
    for (int e = estart + tid; e < eend; e += 512) {
        unsigned int u = aux[e];
        int pos = atomicAdd(&hC[u & 255], 1);
        csr_src[pos] = (int)(u >> 8);
    }
}

// ---------------------------------------------------------------------------
// 2. MFMA: hs1 = bf16( dis * (x @ W1) ); 64-row tile, 4 waves, 16x16x32 bf16.
__global__ __launch_bounds__(256) void k_gemm1(const float* __restrict__ x,
                                               const float* __restrict__ W1,
                                               const float* __restrict__ dis,
                                               unsigned short* __restrict__ hs1) {
    __shared__ unsigned short Asb[64 * 136];   // 17408 B
    __shared__ unsigned short Btb[64 * 136];   // 17408 B (Bt[n][k])
    __shared__ unsigned short Cc[64 * 72];     // 9216 B
    __shared__ float disS[64];
    const int tid = threadIdx.x;
    const int r0 = blockIdx.x * 64;

    if (tid < 64) disS[tid] = (r0 + tid < N_NODES) ? dis[r0 + tid] : 0.f;

    const float4* x4 = (const float4*)x;
#pragma unroll
    for (int p = 0; p < 4; ++p) {
        int idx8 = p * 256 + tid;
        int row = idx8 >> 4, c8 = idx8 & 15;
        float4 v0 = make_float4(0.f, 0.f, 0.f, 0.f), v1 = v0;
        if (r0 + row < N_NODES) {
            v0 = x4[(size_t)(r0 + row) * 32 + c8 * 2];
            v1 = x4[(size_t)(r0 + row) * 32 + c8 * 2 + 1];
        }
        uint4 u;
        u.x = pack2bf(v0.x, v0.y); u.y = pack2bf(v0.z, v0.w);
        u.z = pack2bf(v1.x, v1.y); u.w = pack2bf(v1.z, v1.w);
        *(uint4*)&Asb[row * 136 + c8 * 8] = u;
    }
    for (int idx = tid; idx < IN_F * HID_F; idx += 256) {
        int k = idx >> 6, n = idx & 63;
        Btb[n * 136 + k] = bf1(W1[idx]);
    }
    __syncthreads();

    const int wv = tid >> 6, lane = tid & 63;
    const int m = lane & 15, quad = lane >> 4;
    const int arow = wv * 16 + m;
    f32x4 acc[4] = {};
#pragma unroll
    for (int ks = 0; ks < 4; ++ks) {
        int k0 = ks * 32 + quad * 8;
        bf16x8 af = *(const bf16x8*)&Asb[arow * 136 + k0];
#pragma unroll
        for (int c = 0; c < 4; ++c) {
            bf16x8 bfr = *(const bf16x8*)&Btb[(c * 16 + m) * 136 + k0];
            acc[c] = __builtin_amdgcn_mfma_f32_16x16x32_bf16(af, bfr, acc[c], 0, 0, 0);
        }
    }
#pragma unroll
    for (int c = 0; c < 4; ++c)
#pragma unroll
        for (int r = 0; r < 4; ++r) {
            int rl = wv * 16 + quad * 4 + r;
            Cc[rl * 72 + c * 16 + m] = bf1(acc[c][r] * disS[rl]);
        }
    __syncthreads();
#pragma unroll
    for (int p = 0; p < 2; ++p) {
        int idx = p * 256 + tid;
        int row = idx >> 3, c8 = idx & 7;
        if (r0 + row < N_NODES)
            *(uint4*)&hs1[(size_t)(r0 + row) * 64 + c8 * 8] = *(uint4*)&Cc[row * 72 + c8 * 8];
    }
}

// ---------------------------------------------------------------------------
// 3. gather conv1 (bf16 rows) -> bf16 agg + per-block BN partials (fp32).
__global__ __launch_bounds__(256) void k_gather1(const int* __restrict__ rowptr,
                                                 const int* __restrict__ csr_src,
                                                 const unsigned short* __restrict__ hsb,
                                                 const float* __restrict__ dis,
                                                 const float* __restrict__ b1,
                                                 unsigned short* __restrict__ aggb,
                                                 float* __restrict__ partials) {
    const int tid = threadIdx.x;
    const int g = tid >> 3, q = tid & 7;
    const int n = blockIdx.x * 32 + g;
    const uint4* __restrict__ hs16 = (const uint4*)hsb;   // row = 8 uint4

    const int start = rowptr[n], end = rowptr[n + 1];
    float A0[8] = {}, A1[8] = {}, A2[8] = {}, A3[8] = {};
    {   // self term
        uint4 u = hs16[(size_t)n * 8 + q];
        ADD8(A0, u);
    }
    int i = start;
    for (; i + 3 < end; i += 4) {
        int s0 = csr_src[i + 0], s1 = csr_src[i + 1];
        int s2 = csr_src[i + 2], s3 = csr_src[i + 3];
        uint4 u0 = hs16[(size_t)s0 * 8 + q];
        uint4 u1 = hs16[(size_t)s1 * 8 + q];
        uint4 u2 = hs16[(size_t)s2 * 8 + q];
        uint4 u3 = hs16[(size_t)s3 * 8 + q];
        ADD8(A0, u0); ADD8(A1, u1); ADD8(A2, u2); ADD8(A3, u3);
    }
    for (; i < end; ++i) {
        uint4 u = hs16[(size_t)csr_src[i] * 8 + q];
        ADD8(A0, u);
    }
    const float d = dis[n];
    const float4 blo = ((const float4*)b1)[q * 2];
    const float4 bhi = ((const float4*)b1)[q * 2 + 1];
    float o[8];
    o[0] = fmaf(d, A0[0] + A1[0] + A2[0] + A3[0], blo.x);
    o[1] = fmaf(d, A0[1] + A1[1] + A2[1] + A3[1], blo.y);
    o[2] = fmaf(d, A0[2] + A1[2] + A2[2] + A3[2], blo.z);
    o[3] = fmaf(d, A0[3] + A1[3] + A2[3] + A3[3], blo.w);
    o[4] = fmaf(d, A0[4] + A1[4] + A2[4] + A3[4], bhi.x);
    o[5] = fmaf(d, A0[5] + A1[5] + A2[5] + A3[5], bhi.y);
    o[6] = fmaf(d, A0[6] + A1[6] + A2[6] + A3[6], bhi.z);
    o[7] = fmaf(d, A0[7] + A1[7] + A2[7] + A3[7], bhi.w);
    uint4 ob;
    ob.x = pack2bf(o[0], o[1]); ob.y = pack2bf(o[2], o[3]);
    ob.z = pack2bf(o[4], o[5]); ob.w = pack2bf(o[6], o[7]);
    ((uint4*)aggb)[(size_t)n * 8 + q] = ob;

    __shared__ float4 redA[256], redB[256];   // 8 KB
    redA[tid] = make_float4(o[0], o[1], o[2], o[3]);
    redB[tid] = make_float4(o[4], o[5], o[6], o[7]);
    __syncthreads();
    for (int s = 128; s >= 8; s >>= 1) {
        if (tid < s) {
            redA[tid].x += redA[tid + s].x; redA[tid].y += redA[tid + s].y;
            redA[tid].z += redA[tid + s].z; redA[tid].w += redA[tid + s].w;
            redB[tid].x += redB[tid + s].x; redB[tid].y += redB[tid + s].y;
            redB[tid].z += redB[tid + s].z; redB[tid].w += redB[tid + s].w;
        }
        __syncthreads();
    }
    float4* pr = (float4*)(partials + (size_t)blockIdx.x * 128);
    if (tid < 8) { pr[tid * 2] = redA[tid]; pr[tid * 2 + 1] = redB[tid]; }
    __syncthreads();
    redA[tid] = make_float4(o[0] * o[0], o[1] * o[1], o[2] * o[2], o[3] * o[3]);
    redB[tid] = make_float4(o[4] * o[4], o[5] * o[5], o[6] * o[6], o[7] * o[7]);
    __syncthreads();
    for (int s = 128; s >= 8; s >>= 1) {
        if (tid < s) {
            redA[tid].x += redA[tid + s].x; redA[tid].y += redA[tid + s].y;
            redA[tid].z += redA[tid + s].z; redA[tid].w += redA[tid + s].w;
            redB[tid].x += redB[tid + s].x; redB[tid].y += redB[tid + s].y;
            redB[tid].z += redB[tid + s].z; redB[tid].w += redB[tid + s].w;
        }
        __syncthreads();
    }
    if (tid < 8) { pr[16 + tid * 2] = redA[tid]; pr[16 + tid * 2 + 1] = redB[tid]; }
}

// 3b. reduce partials[NGBLK][128] -> bnstats[128]
__global__ __launch_bounds__(256) void k_bnfinal(const float* __restrict__ partials,
                                                 float* __restrict__ bnstats) {
    const int tid = threadIdx.x;
    const int col = tid & 127;
    const int half = tid >> 7;
    float s = 0.f;
    for (int r = blockIdx.x * 2 + half; r < NGBLK; r += 128)
        s += partials[(size_t)r * 128 + col];
    __shared__ float sh[256];
    sh[tid] = s;
    __syncthreads();
    if (tid < 128) unsafeAtomicAdd(&bnstats[col], sh[tid] + sh[tid + 128]);
}

// ---------------------------------------------------------------------------
// 4. MFMA: hs2 = bf16( dis * (relu(BN(agg_bf16)) @ W2) ); K=64.
__global__ __launch_bounds__(256) void k_gemm2(const unsigned short* __restrict__ aggb,
                                               const float* __restrict__ W2,
                                               const float* __restrict__ dis,
                                               const float* __restrict__ bnw,
                                               const float* __restrict__ bnb,
                                               const float* __restrict__ bnstats,
                                               unsigned short* __restrict__ hs2) {
    __shared__ unsigned short Ab[64 * 72];     // 9216 B
    __shared__ unsigned short Bt2[64 * 72];    // 9216 B
    __shared__ unsigned short Cc[64 * 72];     // 9216 B
    __shared__ float scale_s[64], shift_s[64], disS[64];
    const int tid = threadIdx.x;
    const int r0 = blockIdx.x * 64;

    if (tid < 64) {
        const float invN = 1.0f / (float)N_NODES;
        float mean = bnstats[tid] * invN;
        float var  = bnstats[64 + tid] * invN - mean * mean;
        float sc   = bnw[tid] * rsqrtf(var + BN_EPS);
        scale_s[tid] = sc;
        shift_s[tid] = fmaf(-mean, sc, bnb[tid]);
        disS[tid] = (r0 + tid < N_NODES) ? dis[r0 + tid] : 0.f;
    }
    for (int idx = tid; idx < HID_F * OUT_F; idx += 256) {
        int k = idx >> 6, n = idx & 63;
        Bt2[n * 72 + k] = bf1(W2[idx]);
    }
    __syncthreads();   // scale_s/shift_s ready before A-stage uses them

    const uint4* a16 = (const uint4*)aggb;     // row = 8 uint4 (64 bf16)
#pragma unroll
    for (int p = 0; p < 2; ++p) {
        int idx = p * 256 + tid;               // 512 uint4 total
        int row = idx >> 3, q = idx & 7;
        uint4 u = make_uint4(0, 0, 0, 0);
        if (r0 + row < N_NODES) u = a16[(size_t)(r0 + row) * 8 + q];
        int k0 = q * 8;
        float v[8];
        v[0] = bflo(u.x); v[1] = bfhi(u.x); v[2] = bflo(u.y); v[3] = bfhi(u.y);
        v[4] = bflo(u.z); v[5] = bfhi(u.z); v[6] = bflo(u.w); v[7] = bfhi(u.w);
        uint4 o;
        float w0 = fmaxf(fmaf(v[0], scale_s[k0 + 0], shift_s[k0 + 0]), 0.f);
        float w1 = fmaxf(fmaf(v[1], scale_s[k0 + 1], shift_s[k0 + 1]), 0.f);
        float w2 = fmaxf(fmaf(v[2], scale_s[k0 + 2], shift_s[k0 + 2]), 0.f);
        float w3 = fmaxf(fmaf(v[3], scale_s[k0 + 3], shift_s[k0 + 3]), 0.f);
        float w4 = fmaxf(fmaf(v[4], scale_s[k0 + 4], shift_s[k0 + 4]), 0.f);
        float w5 = fmaxf(fmaf(v[5], scale_s[k0 + 5], shift_s[k0 + 5]), 0.f);
        float w6 = fmaxf(fmaf(v[6], scale_s[k0 + 6], shift_s[k0 + 6]), 0.f);
        float w7 = fmaxf(fmaf(v[7], scale_s[k0 + 7], shift_s[k0 + 7]), 0.f);
        o.x = pack2bf(w0, w1); o.y = pack2bf(w2, w3);
        o.z = pack2bf(w4, w5); o.w = pack2bf(w6, w7);
        *(uint4*)&Ab[row * 72 + q * 8] = o;
    }
    __syncthreads();

    const int wv = tid >> 6, lane = tid & 63;
    const int m = lane & 15, quad = lane >> 4;
    const int arow = wv * 16 + m;
    f32x4 acc[4] = {};
#pragma unroll
    for (int ks = 0; ks < 2; ++ks) {
        int k0 = ks * 32 + quad * 8;
        bf16x8 af = *(const bf16x8*)&Ab[arow * 72 + k0];
#pragma unroll
        for (int c = 0; c < 4; ++c) {
            bf16x8 bfr = *(const bf16x8*)&Bt2[(c * 16 + m) * 72 + k0];
            acc[c] = __builtin_amdgcn_mfma_f32_16x16x32_bf16(af, bfr, acc[c], 0, 0, 0);
        }
    }
#pragma unroll
    for (int c = 0; c < 4; ++c)
#pragma unroll
        for (int r = 0; r < 4; ++r) {
            int rl = wv * 16 + quad * 4 + r;
            Cc[rl * 72 + c * 16 + m] = bf1(acc[c][r] * disS[rl]);
        }
    __syncthreads();
#pragma unroll
    for (int p = 0; p < 2; ++p) {
        int idx = p * 256 + tid;
        int row = idx >> 3, c8 = idx & 7;
        if (r0 + row < N_NODES)
            *(uint4*)&hs2[(size_t)(r0 + row) * 64 + c8 * 8] = *(uint4*)&Cc[row * 72 + c8 * 8];
    }
}

// ---------------------------------------------------------------------------
// 5. gather conv2 (bf16 rows) + final epilogue -> fp32 out
__global__ __launch_bounds__(256) void k_gather2(const int* __restrict__ rowptr,
                                                 const int* __restrict__ csr_src,
                                                 const unsigned short* __restrict__ hsb,
                                                 const float* __restrict__ dis,
                                                 const float* __restrict__ b2,
                                                 float* __restrict__ out) {
    const int tid = threadIdx.x;
    const int g = tid >> 3, q = tid & 7;
    const int n = blockIdx.x * 32 + g;
    const uint4* __restrict__ hs16 = (const uint4*)hsb;

    const int start = rowptr[n], end = rowptr[n + 1];
    float A0[8] = {}, A1[8] = {}, A2[8] = {}, A3[8] = {};
    {
        uint4 u = hs16[(size_t)n * 8 + q];
        ADD8(A0, u);
    }
    int i = start;
    for (; i + 3 < end; i += 4) {
        int s0 = csr_src[i + 0], s1 = csr_src[i + 1];
        int s2 = csr_src[i + 2], s3 = csr_src[i + 3];
        uint4 u0 = hs16[(size_t)s0 * 8 + q];
        uint4 u1 = hs16[(size_t)s1 * 8 + q];
        uint4 u2 = hs16[(size_t)s2 * 8 + q];
        uint4 u3 = hs16[(size_t)s3 * 8 + q];
        ADD8(A0, u0); ADD8(A1, u1); ADD8(A2, u2); ADD8(A3, u3);
    }
    for (; i < end; ++i) {
        uint4 u = hs16[(size_t)csr_src[i] * 8 + q];
        ADD8(A0, u);
    }
    const float d = dis[n];
    const float4 blo = ((const float4*)b2)[q * 2];
    const float4 bhi = ((const float4*)b2)[q * 2 + 1];
    float4 o0, o1;
    o0.x = fmaf(d, A0[0] + A1[0] + A2[0] + A3[0], blo.x);
    o0.y = fmaf(d, A0[1] + A1[1] + A2[1] + A3[1], blo.y);
    o0.z = fmaf(d, A0[2] + A1[2] + A2[2] + A3[2], blo.z);
    o0.w = fmaf(d, A0[3] + A1[3] + A2[3] + A3[3], blo.w);
    o1.x = fmaf(d, A0[4] + A1[4] + A2[4] + A3[4], bhi.x);
    o1.y = fmaf(d, A0[5] + A1[5] + A2[5] + A3[5], bhi.y);
    o1.z = fmaf(d, A0[6] + A1[6] + A2[6] + A3[6], bhi.z);
    o1.w = fmaf(d, A0[7] + A1[7] + A2[7] + A3[7], bhi.w);
    float4* op = (float4*)(out + (size_t)n * OUT_F + q * 8);
    op[0] = o0;
    op[1] = o1;
}

// ---------------------------------------------------------------------------
extern "C" void kernel_launch(void* const* d_in, const int* in_sizes, int n_in,
                              void* d_out, int out_size, void* d_ws, size_t ws_size,
                              hipStream_t stream) {
    const float* x   = (const float*)d_in[0];
    const int*   ei  = (const int*)d_in[1];
    const float* W1  = (const float*)d_in[2];
    const float* b1  = (const float*)d_in[3];
    const float* bnw = (const float*)d_in[4];
    const float* bnb = (const float*)d_in[5];
    const float* W2  = (const float*)d_in[6];
    const float* b2  = (const float*)d_in[7];
    float* out = (float*)d_out;

    // workspace layout (floats, 16B-aligned segments):
    float* ws = (float*)d_ws;
    float*        dis     = ws;                               // 100352
    int*          rowptr  = (int*)(ws + 100352);              // 100608 (N+1 used)
    int*          coff    = (int*)(ws + 100352 + 100608);     // 512 (NBUK+1 used)
    int*          ccur    = (int*)(ws + 100352 + 100608 + 512);          // 512
    float*        bnstats = ws + 100352 + 100608 + 512 + 512;            // 128
    int*          csr_src = (int*)(ws + 100352 + 100608 + 512 + 512 + 128); // 1.6M
    float*        bufA    = ws + 100352 + 100608 + 512 + 512 + 128 + 1600000; // N*64 fp32 region
    float*        bufB    = bufA + (size_t)N_NODES * HID_F;                   // N*64 region
    unsigned int*   aux  = (unsigned int*)bufA;    // CSR-build scratch, dead before gemm1
    unsigned short* hsb  = (unsigned short*)bufA;  // bf16 hs1, then bf16 hs2 (12.8 MB)
    unsigned short* aggb = (unsigned short*)bufB;  // bf16 agg (12.8 MB)
    float* partials = out;                         // NGBLK*128 floats, dead until gather2

    const int* srcv = ei;
    const int* dstv = ei + E_EDGES;

    {   // cooperative CSR build (replaces memsets + 4 kernels)
        void* args[] = {(void*)&srcv, (void*)&dstv, (void*)&coff, (void*)&ccur,
                        (void*)&aux, (void*)&rowptr, (void*)&dis, (void*)&csr_src,
                        (void*)&bnstats};
        hipLaunchCooperativeKernel((void*)k_csr, dim3(NBUK), dim3(512), args, 0, stream);
    }

    k_gemm1  <<<NMBLK, 256, 0, stream>>>(x, W1, dis, hsb);
    k_gather1<<<NGBLK, 256, 0, stream>>>(rowptr, csr_src, hsb, dis, b1, aggb, partials);
    k_bnfinal<<<64, 256, 0, stream>>>(partials, bnstats);
    k_gemm2  <<<NMBLK, 256, 0, stream>>>(aggb, W2, dis, bnw, bnb, bnstats, hsb);
    k_gather2<<<NGBLK, 256, 0, stream>>>(rowptr, csr_src, hsb, dis, b2, out);
}

// Round 8
// 252.000 us; speedup vs baseline: 1.7518x; 1.7518x over previous
//
#include <hip/hip_runtime.h>

#define N_NODES 100000
#define E_EDGES 1600000
#define IN_F    128
#define HID_F   64
#define OUT_F   64
#define BN_EPS  1e-5f
#define NBUK    391    // ceil(N/256) coarse buckets (256 nodes each)
#define CHUNK   6250   // E / 256 blocks
#define NGBLK   3125   // N/32 gather blocks (32 nodes per block, 8 lanes/node)
#define NMBLK   1563   // ceil(N/64) gemm blocks

typedef __bf16 bf16x8 __attribute__((ext_vector_type(8)));
typedef float  f32x4  __attribute__((ext_vector_type(4)));

// bf16 helpers ---------------------------------------------------------------
__device__ __forceinline__ float bflo(unsigned int u) { return __uint_as_float(u << 16); }
__device__ __forceinline__ float bfhi(unsigned int u) { return __uint_as_float(u & 0xFFFF0000u); }
__device__ __forceinline__ unsigned int pack2bf(float a, float b) {
    unsigned int ua = __float_as_uint(a), ub = __float_as_uint(b);
    ua = (ua + 0x7fffu + ((ua >> 16) & 1u)) >> 16;          // RNE
    ub = (ub + 0x7fffu + ((ub >> 16) & 1u)) >> 16;
    return ua | (ub << 16);
}
__device__ __forceinline__ unsigned short bf1(float a) {
    unsigned int ua = __float_as_uint(a);
    return (unsigned short)((ua + 0x7fffu + ((ua >> 16) & 1u)) >> 16);
}
#define ADD8(A, u)                                           \
    do {                                                     \
        A[0] += bflo((u).x); A[1] += bfhi((u).x);            \
        A[2] += bflo((u).y); A[3] += bfhi((u).y);            \
        A[4] += bflo((u).z); A[5] += bfhi((u).z);            \
        A[6] += bflo((u).w); A[7] += bfhi((u).w);            \
    } while (0)

// ---------------------------------------------------------------------------
// 1. coarse histogram, non-atomic output: histbuf[block][391]
__global__ __launch_bounds__(512) void k_chist(const int* __restrict__ dstv,
                                               int* __restrict__ histbuf) {
    __shared__ int h[NBUK];
    const int tid = threadIdx.x;
    const int e0 = blockIdx.x * CHUNK;
    for (int b = tid; b < NBUK; b += 512) h[b] = 0;
    __syncthreads();
    for (int t = tid; t < CHUNK; t += 512)
        atomicAdd(&h[dstv[e0 + t] >> 8], 1);
    __syncthreads();
    for (int b = tid; b < NBUK; b += 512)
        histbuf[blockIdx.x * NBUK + b] = h[b];
}

// 2. reduce histbuf -> bucket counts, exclusive scan -> coff + ccur
__global__ __launch_bounds__(512) void k_cscan(const int* __restrict__ histbuf,
                                               int* __restrict__ coff,
                                               int* __restrict__ ccur) {
    __shared__ int sh[512];
    const int tid = threadIdx.x;
    int v = 0;
    if (tid < NBUK)
        for (int b = 0; b < 256; ++b) v += histbuf[b * NBUK + tid];
    sh[tid] = v;
    __syncthreads();
    for (int off = 1; off < 512; off <<= 1) {
        int t = (tid >= off) ? sh[tid - off] : 0;
        __syncthreads();
        sh[tid] += t;
        __syncthreads();
    }
    int excl = sh[tid] - v;
    if (tid < NBUK) { coff[tid] = excl; ccur[tid] = excl; }
    if (tid == 0) coff[NBUK] = E_EDGES;
}

// 3. bucket scatter: aux[pos] = src<<8 | (dst&255), coarse-bucket-grouped.
__global__ __launch_bounds__(512) void k_bucket(const int* __restrict__ srcv,
                                                const int* __restrict__ dstv,
                                                int* __restrict__ ccur,
                                                unsigned int* __restrict__ aux) {
    __shared__ int dl[CHUNK];                  // 25 KB
    __shared__ int hist[NBUK], base[NBUK], lcur[NBUK];
    const int tid = threadIdx.x;
    const int e0 = blockIdx.x * CHUNK;
    for (int b = tid; b < NBUK; b += 512) hist[b] = 0;
    __syncthreads();
    for (int t = tid; t < CHUNK; t += 512) {
        int d = dstv[e0 + t];
        dl[t] = d;
        atomicAdd(&hist[d >> 8], 1);
    }
    __syncthreads();
    for (int b = tid; b < NBUK; b += 512) {
        int h = hist[b];
        if (h) base[b] = atomicAdd(&ccur[b], h);
        lcur[b] = 0;
    }
    __syncthreads();
    for (int t = tid; t < CHUNK; t += 512) {
        int d = dl[t];
        int b = d >> 8;
        int off = atomicAdd(&lcur[b], 1);
        aux[base[b] + off] = ((unsigned int)srcv[e0 + t] << 8) | (unsigned int)(d & 255);
    }
}

// 4. per-bucket: per-node counts (LDS) -> rowptr + dis, then fine CSR placement.
__global__ __launch_bounds__(256) void k_csrnode(const int* __restrict__ coff,
                                                 const unsigned int* __restrict__ aux,
                                                 int* __restrict__ rowptr,
                                                 float* __restrict__ dis,
                                                 int* __restrict__ csr_src) {
    __shared__ int c0[256], sc[256], cur[256];
    const int tid = threadIdx.x;
    const int n0 = blockIdx.x * 256;
    const int nn = min(256, N_NODES - n0);
    const int estart = coff[blockIdx.x];
    const int eend   = coff[blockIdx.x + 1];
    c0[tid] = 0;
    __syncthreads();
    for (int e = estart + tid; e < eend; e += 256)
        atomicAdd(&c0[aux[e] & 255], 1);
    __syncthreads();
    int v = c0[tid];
    sc[tid] = v;
    __syncthreads();
    for (int off = 1; off < 256; off <<= 1) {
        int t = (tid >= off) ? sc[tid - off] : 0;
        __syncthreads();
        sc[tid] += t;
        __syncthreads();
    }
    int excl = sc[tid] - v;
    if (tid < nn) {
        int p = estart + excl;
        rowptr[n0 + tid] = p;
        cur[tid] = p;
        dis[n0 + tid] = rsqrtf((float)v + 1.0f);
    }
    if (blockIdx.x == NBUK - 1 && tid == 0) rowptr[N_NODES] = E_EDGES;
    __syncthreads();
    for (int e = estart + tid; e < eend; e += 256) {
        unsigned int u = aux[e];
        int pos = atomicAdd(&cur[u & 255], 1);
        csr_src[pos] = (int)(u >> 8);
    }
}

// ---------------------------------------------------------------------------
// 5. MFMA: hs1 = bf16( dis * (x @ W1) ); 64-row tile, 4 waves, 16x16x32 bf16.
__global__ __launch_bounds__(256) void k_gemm1(const float* __restrict__ x,
                                               const float* __restrict__ W1,
                                               const float* __restrict__ dis,
                                               unsigned short* __restrict__ hs1) {
    __shared__ unsigned short Asb[64 * 136];   // 17408 B
    __shared__ unsigned short Btb[64 * 136];   // 17408 B (Bt[n][k])
    __shared__ unsigned short Cc[64 * 72];     // 9216 B
    __shared__ float disS[64];
    const int tid = threadIdx.x;
    const int r0 = blockIdx.x * 64;

    if (tid < 64) disS[tid] = (r0 + tid < N_NODES) ? dis[r0 + tid] : 0.f;

    const float4* x4 = (const float4*)x;
#pragma unroll
    for (int p = 0; p < 4; ++p) {
        int idx8 = p * 256 + tid;
        int row = idx8 >> 4, c8 = idx8 & 15;
        float4 v0 = make_float4(0.f, 0.f, 0.f, 0.f), v1 = v0;
        if (r0 + row < N_NODES) {
            v0 = x4[(size_t)(r0 + row) * 32 + c8 * 2];
            v1 = x4[(size_t)(r0 + row) * 32 + c8 * 2 + 1];
        }
        uint4 u;
        u.x = pack2bf(v0.x, v0.y); u.y = pack2bf(v0.z, v0.w);
        u.z = pack2bf(v1.x, v1.y); u.w = pack2bf(v1.z, v1.w);
        *(uint4*)&Asb[row * 136 + c8 * 8] = u;
    }
    for (int idx = tid; idx < IN_F * HID_F; idx += 256) {
        int k = idx >> 6, n = idx & 63;
        Btb[n * 136 + k] = bf1(W1[idx]);
    }
    __syncthreads();

    const int wv = tid >> 6, lane = tid & 63;
    const int m = lane & 15, quad = lane >> 4;
    const int arow = wv * 16 + m;
    f32x4 acc[4] = {};
#pragma unroll
    for (int ks = 0; ks < 4; ++ks) {
        int k0 = ks * 32 + quad * 8;
        bf16x8 af = *(const bf16x8*)&Asb[arow * 136 + k0];
#pragma unroll
        for (int c = 0; c < 4; ++c) {
            bf16x8 bfr = *(const bf16x8*)&Btb[(c * 16 + m) * 136 + k0];
            acc[c] = __builtin_amdgcn_mfma_f32_16x16x32_bf16(af, bfr, acc[c], 0, 0, 0);
        }
    }
#pragma unroll
    for (int c = 0; c < 4; ++c)
#pragma unroll
        for (int r = 0; r < 4; ++r) {
            int rl = wv * 16 + quad * 4 + r;
            Cc[rl * 72 + c * 16 + m] = bf1(acc[c][r] * disS[rl]);
        }
    __syncthreads();
#pragma unroll
    for (int p = 0; p < 2; ++p) {
        int idx = p * 256 + tid;
        int row = idx >> 3, c8 = idx & 7;
        if (r0 + row < N_NODES)
            *(uint4*)&hs1[(size_t)(r0 + row) * 64 + c8 * 8] = *(uint4*)&Cc[row * 72 + c8 * 8];
    }
}

// ---------------------------------------------------------------------------
// 6. gather conv1 (bf16 rows, 8-deep load pipeline) -> bf16 agg + BN partials.
__global__ __launch_bounds__(256) void k_gather1(const int* __restrict__ rowptr,
                                                 const int* __restrict__ csr_src,
                                                 const unsigned short* __restrict__ hsb,
                                                 const float* __restrict__ dis,
                                                 const float* __restrict__ b1,
                                                 unsigned short* __restrict__ aggb,
                                                 float* __restrict__ partials) {
    const int tid = threadIdx.x;
    const int g = tid >> 3, q = tid & 7;
    const int n = blockIdx.x * 32 + g;
    const uint4* __restrict__ hs16 = (const uint4*)hsb;   // row = 8 uint4

    const int start = rowptr[n], end = rowptr[n + 1];
    float A0[8] = {}, A1[8] = {}, A2[8] = {}, A3[8] = {};
    {   // self term
        uint4 u = hs16[(size_t)n * 8 + q];
        ADD8(A0, u);
    }
    int i = start;
    for (; i + 7 < end; i += 8) {
        int s0 = csr_src[i + 0], s1 = csr_src[i + 1];
        int s2 = csr_src[i + 2], s3 = csr_src[i + 3];
        int s4 = csr_src[i + 4], s5 = csr_src[i + 5];
        int s6 = csr_src[i + 6], s7 = csr_src[i + 7];
        uint4 u0 = hs16[(size_t)s0 * 8 + q];
        uint4 u1 = hs16[(size_t)s1 * 8 + q];
        uint4 u2 = hs16[(size_t)s2 * 8 + q];
        uint4 u3 = hs16[(size_t)s3 * 8 + q];
        uint4 u4 = hs16[(size_t)s4 * 8 + q];
        uint4 u5 = hs16[(size_t)s5 * 8 + q];
        uint4 u6 = hs16[(size_t)s6 * 8 + q];
        uint4 u7 = hs16[(size_t)s7 * 8 + q];
        ADD8(A0, u0); ADD8(A1, u1); ADD8(A2, u2); ADD8(A3, u3);
        ADD8(A0, u4); ADD8(A1, u5); ADD8(A2, u6); ADD8(A3, u7);
    }
    if (i + 3 < end) {
        int s0 = csr_src[i + 0], s1 = csr_src[i + 1];
        int s2 = csr_src[i + 2], s3 = csr_src[i + 3];
        uint4 u0 = hs16[(size_t)s0 * 8 + q];
        uint4 u1 = hs16[(size_t)s1 * 8 + q];
        uint4 u2 = hs16[(size_t)s2 * 8 + q];
        uint4 u3 = hs16[(size_t)s3 * 8 + q];
        ADD8(A0, u0); ADD8(A1, u1); ADD8(A2, u2); ADD8(A3, u3);
        i += 4;
    }
    for (; i < end; ++i) {
        uint4 u = hs16[(size_t)csr_src[i] * 8 + q];
        ADD8(A0, u);
    }
    const float d = dis[n];
    const float4 blo = ((const float4*)b1)[q * 2];
    const float4 bhi = ((const float4*)b1)[q * 2 + 1];
    float o[8];
    o[0] = fmaf(d, A0[0] + A1[0] + A2[0] + A3[0], blo.x);
    o[1] = fmaf(d, A0[1] + A1[1] + A2[1] + A3[1], blo.y);
    o[2] = fmaf(d, A0[2] + A1[2] + A2[2] + A3[2], blo.z);
    o[3] = fmaf(d, A0[3] + A1[3] + A2[3] + A3[3], blo.w);
    o[4] = fmaf(d, A0[4] + A1[4] + A2[4] + A3[4], bhi.x);
    o[5] = fmaf(d, A0[5] + A1[5] + A2[5] + A3[5], bhi.y);
    o[6] = fmaf(d, A0[6] + A1[6] + A2[6] + A3[6], bhi.z);
    o[7] = fmaf(d, A0[7] + A1[7] + A2[7] + A3[7], bhi.w);
    uint4 ob;
    ob.x = pack2bf(o[0], o[1]); ob.y = pack2bf(o[2], o[3]);
    ob.z = pack2bf(o[4], o[5]); ob.w = pack2bf(o[6], o[7]);
    ((uint4*)aggb)[(size_t)n * 8 + q] = ob;

    __shared__ float4 redA[256], redB[256];   // 8 KB
    redA[tid] = make_float4(o[0], o[1], o[2], o[3]);
    redB[tid] = make_float4(o[4], o[5], o[6], o[7]);
    __syncthreads();
    for (int s = 128; s >= 8; s >>= 1) {
        if (tid < s) {
            redA[tid].x += redA[tid + s].x; redA[tid].y += redA[tid + s].y;
            redA[tid].z += redA[tid + s].z; redA[tid].w += redA[tid + s].w;
            redB[tid].x += redB[tid + s].x; redB[tid].y += redB[tid + s].y;
            redB[tid].z += redB[tid + s].z; redB[tid].w += redB[tid + s].w;
        }
        __syncthreads();
    }
    float4* pr = (float4*)(partials + (size_t)blockIdx.x * 128);
    if (tid < 8) { pr[tid * 2] = redA[tid]; pr[tid * 2 + 1] = redB[tid]; }
    __syncthreads();
    redA[tid] = make_float4(o[0] * o[0], o[1] * o[1], o[2] * o[2], o[3] * o[3]);
    redB[tid] = make_float4(o[4] * o[4], o[5] * o[5], o[6] * o[6], o[7] * o[7]);
    __syncthreads();
    for (int s = 128; s >= 8; s >>= 1) {
        if (tid < s) {
            redA[tid].x += redA[tid + s].x; redA[tid].y += redA[tid + s].y;
            redA[tid].z += redA[tid + s].z; redA[tid].w += redA[tid + s].w;
            redB[tid].x += redB[tid + s].x; redB[tid].y += redB[tid + s].y;
            redB[tid].z += redB[tid + s].z; redB[tid].w += redB[tid + s].w;
        }
        __syncthreads();
    }
    if (tid < 8) { pr[16 + tid * 2] = redA[tid]; pr[16 + tid * 2 + 1] = redB[tid]; }
}

// 6b. reduce partials[NGBLK][128] -> bnstats[128]; block = column, no atomics.
__global__ __launch_bounds__(256) void k_bnfinal(const float* __restrict__ partials,
                                                 float* __restrict__ bnstats) {
    const int c = blockIdx.x;          // 0..127
    const int tid = threadIdx.x;
    float s = 0.f;
    for (int r = tid; r < NGBLK; r += 256)
        s += partials[(size_t)r * 128 + c];
    __shared__ float sh[256];
    sh[tid] = s;
    __syncthreads();
    for (int st = 128; st > 0; st >>= 1) {
        if (tid < st) sh[tid] += sh[tid + st];
        __syncthreads();
    }
    if (tid == 0) bnstats[c] = sh[0];
}

// ---------------------------------------------------------------------------
// 7. MFMA: hs2 = bf16( dis * (relu(BN(agg_bf16)) @ W2) ); K=64.
__global__ __launch_bounds__(256) void k_gemm2(const unsigned short* __restrict__ aggb,
                                               const float* __restrict__ W2,
                                               const float* __restrict__ dis,
                                               const float* __restrict__ bnw,
                                               const float* __restrict__ bnb,
                                               const float* __restrict__ bnstats,
                                               unsigned short* __restrict__ hs2) {
    __shared__ unsigned short Ab[64 * 72];     // 9216 B
    __shared__ unsigned short Bt2[64 * 72];    // 9216 B
    __shared__ unsigned short Cc[64 * 72];     // 9216 B
    __shared__ float scale_s[64], shift_s[64], disS[64];
    const int tid = threadIdx.x;
    const int r0 = blockIdx.x * 64;

    if (tid < 64) {
        const float invN = 1.0f / (float)N_NODES;
        float mean = bnstats[tid] * invN;
        float var  = bnstats[64 + tid] * invN - mean * mean;
        float sc   = bnw[tid] * rsqrtf(var + BN_EPS);
        scale_s[tid] = sc;
        shift_s[tid] = fmaf(-mean, sc, bnb[tid]);
        disS[tid] = (r0 + tid < N_NODES) ? dis[r0 + tid] : 0.f;
    }
    for (int idx = tid; idx < HID_F * OUT_F; idx += 256) {
        int k = idx >> 6, n = idx & 63;
        Bt2[n * 72 + k] = bf1(W2[idx]);
    }
    __syncthreads();   // scale_s/shift_s ready before A-stage uses them

    const uint4* a16 = (const uint4*)aggb;     // row = 8 uint4 (64 bf16)
#pragma unroll
    for (int p = 0; p < 2; ++p) {
        int idx = p * 256 + tid;               // 512 uint4 total
        int row = idx >> 3, q = idx & 7;
        uint4 u = make_uint4(0, 0, 0, 0);
        if (r0 + row < N_NODES) u = a16[(size_t)(r0 + row) * 8 + q];
        int k0 = q * 8;
        float v[8];
        v[0] = bflo(u.x); v[1] = bfhi(u.x); v[2] = bflo(u.y); v[3] = bfhi(u.y);
        v[4] = bflo(u.z); v[5] = bfhi(u.z); v[6] = bflo(u.w); v[7] = bfhi(u.w);
        uint4 o;
        float w0 = fmaxf(fmaf(v[0], scale_s[k0 + 0], shift_s[k0 + 0]), 0.f);
        float w1 = fmaxf(fmaf(v[1], scale_s[k0 + 1], shift_s[k0 + 1]), 0.f);
        float w2 = fmaxf(fmaf(v[2], scale_s[k0 + 2], shift_s[k0 + 2]), 0.f);
        float w3 = fmaxf(fmaf(v[3], scale_s[k0 + 3], shift_s[k0 + 3]), 0.f);
        float w4 = fmaxf(fmaf(v[4], scale_s[k0 + 4], shift_s[k0 + 4]), 0.f);
        float w5 = fmaxf(fmaf(v[5], scale_s[k0 + 5], shift_s[k0 + 5]), 0.f);
        float w6 = fmaxf(fmaf(v[6], scale_s[k0 + 6], shift_s[k0 + 6]), 0.f);
        float w7 = fmaxf(fmaf(v[7], scale_s[k0 + 7], shift_s[k0 + 7]), 0.f);
        o.x = pack2bf(w0, w1); o.y = pack2bf(w2, w3);
        o.z = pack2bf(w4, w5); o.w = pack2bf(w6, w7);
        *(uint4*)&Ab[row * 72 + q * 8] = o;
    }
    __syncthreads();

    const int wv = tid >> 6, lane = tid & 63;
    const int m = lane & 15, quad = lane >> 4;
    const int arow = wv * 16 + m;
    f32x4 acc[4] = {};
#pragma unroll
    for (int ks = 0; ks < 2; ++ks) {
        int k0 = ks * 32 + quad * 8;
        bf16x8 af = *(const bf16x8*)&Ab[arow * 72 + k0];
#pragma unroll
        for (int c = 0; c < 4; ++c) {
            bf16x8 bfr = *(const bf16x8*)&Bt2[(c * 16 + m) * 72 + k0];
            acc[c] = __builtin_amdgcn_mfma_f32_16x16x32_bf16(af, bfr, acc[c], 0, 0, 0);
        }
    }
#pragma unroll
    for (int c = 0; c < 4; ++c)
#pragma unroll
        for (int r = 0; r < 4; ++r) {
            int rl = wv * 16 + quad * 4 + r;
            Cc[rl * 72 + c * 16 + m] = bf1(acc[c][r] * disS[rl]);
        }
    __syncthreads();
#pragma unroll
    for (int p = 0; p < 2; ++p) {
        int idx = p * 256 + tid;
        int row = idx >> 3, c8 = idx & 7;
        if (r0 + row < N_NODES)
            *(uint4*)&hs2[(size_t)(r0 + row) * 64 + c8 * 8] = *(uint4*)&Cc[row * 72 + c8 * 8];
    }
}

// ---------------------------------------------------------------------------
// 8. gather conv2 (bf16 rows, 8-deep pipeline) + final epilogue -> fp32 out
__global__ __launch_bounds__(256) void k_gather2(const int* __restrict__ rowptr,
                                                 const int* __restrict__ csr_src,
                                                 const unsigned short* __restrict__ hsb,
                                                 const float* __restrict__ dis,
                                                 const float* __restrict__ b2,
                                                 float* __restrict__ out) {
    const int tid = threadIdx.x;
    const int g = tid >> 3, q = tid & 7;
    const int n = blockIdx.x * 32 + g;
    const uint4* __restrict__ hs16 = (const uint4*)hsb;

    const int start = rowptr[n], end = rowptr[n + 1];
    float A0[8] = {}, A1[8] = {}, A2[8] = {}, A3[8] = {};
    {
        uint4 u = hs16[(size_t)n * 8 + q];
        ADD8(A0, u);
    }
    int i = start;
    for (; i + 7 < end; i += 8) {
        int s0 = csr_src[i + 0], s1 = csr_src[i + 1];
        int s2 = csr_src[i + 2], s3 = csr_src[i + 3];
        int s4 = csr_src[i + 4], s5 = csr_src[i + 5];
        int s6 = csr_src[i + 6], s7 = csr_src[i + 7];
        uint4 u0 = hs16[(size_t)s0 * 8 + q];
        uint4 u1 = hs16[(size_t)s1 * 8 + q];
        uint4 u2 = hs16[(size_t)s2 * 8 + q];
        uint4 u3 = hs16[(size_t)s3 * 8 + q];
        uint4 u4 = hs16[(size_t)s4 * 8 + q];
        uint4 u5 = hs16[(size_t)s5 * 8 + q];
        uint4 u6 = hs16[(size_t)s6 * 8 + q];
        uint4 u7 = hs16[(size_t)s7 * 8 + q];
        ADD8(A0, u0); ADD8(A1, u1); ADD8(A2, u2); ADD8(A3, u3);
        ADD8(A0, u4); ADD8(A1, u5); ADD8(A2, u6); ADD8(A3, u7);
    }
    if (i + 3 < end) {
        int s0 = csr_src[i + 0], s1 = csr_src[i + 1];
        int s2 = csr_src[i + 2], s3 = csr_src[i + 3];
        uint4 u0 = hs16[(size_t)s0 * 8 + q];
        uint4 u1 = hs16[(size_t)s1 * 8 + q];
        uint4 u2 = hs16[(size_t)s2 * 8 + q];
        uint4 u3 = hs16[(size_t)s3 * 8 + q];
        ADD8(A0, u0); ADD8(A1, u1); ADD8(A2, u2); ADD8(A3, u3);
        i += 4;
    }
    for (; i < end; ++i) {
        uint4 u = hs16[(size_t)csr_src[i] * 8 + q];
        ADD8(A0, u);
    }
    const float d = dis[n];
    const float4 blo = ((const float4*)b2)[q * 2];
    const float4 bhi = ((const float4*)b2)[q * 2 + 1];
    float4 o0, o1;
    o0.x = fmaf(d, A0[0] + A1[0] + A2[0] + A3[0], blo.x);
    o0.y = fmaf(d, A0[1] + A1[1] + A2[1] + A3[1], blo.y);
    o0.z = fmaf(d, A0[2] + A1[2] + A2[2] + A3[2], blo.z);
    o0.w = fmaf(d, A0[3] + A1[3] + A2[3] + A3[3], blo.w);
    o1.x = fmaf(d, A0[4] + A1[4] + A2[4] + A3[4], bhi.x);
    o1.y = fmaf(d, A0[5] + A1[5] + A2[5] + A3[5], bhi.y);
    o1.z = fmaf(d, A0[6] + A1[6] + A2[6] + A3[6], bhi.z);
    o1.w = fmaf(d, A0[7] + A1[7] + A2[7] + A3[7], bhi.w);
    float4* op = (float4*)(out + (size_t)n * OUT_F + q * 8);
    op[0] = o0;
    op[1] = o1;
}

// ---------------------------------------------------------------------------
extern "C" void kernel_launch(void* const* d_in, const int* in_sizes, int n_in,
                              void* d_out, int out_size, void* d_ws, size_t ws_size,
                              hipStream_t stream) {
    const float* x   = (const float*)d_in[0];
    const int*   ei  = (const int*)d_in[1];
    const float* W1  = (const float*)d_in[2];
    const float* b1  = (const float*)d_in[3];
    const float* bnw = (const float*)d_in[4];
    const float* bnb = (const float*)d_in[5];
    const float* W2  = (const float*)d_in[6];
    const float* b2  = (const float*)d_in[7];
    float* out = (float*)d_out;

    // workspace layout (floats, 16B-aligned segments):
    float* ws = (float*)d_ws;
    float*        dis     = ws;                               // 100352
    int*          rowptr  = (int*)(ws + 100352);              // 100608 (N+1 used)
    int*          coff    = (int*)(ws + 200960);              // 512 (NBUK+1 used)
    int*          ccur    = (int*)(ws + 201472);              // 512
    float*        bnstats = ws + 201984;                      // 128
    int*          histbuf = (int*)(ws + 202112);              // 256*391 -> 100352
    int*          csr_src = (int*)(ws + 302464);              // 1.6M
    float*        bufA    = ws + 1902464;                     // N*64 fp32 region
    float*        bufB    = bufA + (size_t)N_NODES * HID_F;   // N*64 region
    unsigned int*   aux  = (unsigned int*)bufA;    // CSR-build scratch, dead before gemm1
    unsigned short* hsb  = (unsigned short*)bufA;  // bf16 hs1, then bf16 hs2 (12.8 MB)
    unsigned short* aggb = (unsigned short*)bufB;  // bf16 agg (12.8 MB)
    float* partials = out;                         // NGBLK*128 floats, dead until gather2

    const int* srcv = ei;
    const int* dstv = ei + E_EDGES;

    k_chist  <<<256, 512, 0, stream>>>(dstv, histbuf);
    k_cscan  <<<1, 512, 0, stream>>>(histbuf, coff, ccur);
    k_bucket <<<256, 512, 0, stream>>>(srcv, dstv, ccur, aux);
    k_csrnode<<<NBUK, 256, 0, stream>>>(coff, aux, rowptr, dis, csr_src);

    k_gemm1  <<<NMBLK, 256, 0, stream>>>(x, W1, dis, hsb);
    k_gather1<<<NGBLK, 256, 0, stream>>>(rowptr, csr_src, hsb, dis, b1, aggb, partials);
    k_bnfinal<<<128, 256, 0, stream>>>(partials, bnstats);
    k_gemm2  <<<NMBLK, 256, 0, stream>>>(aggb, W2, dis, bnw, bnb, bnstats, hsb);
    k_gather2<<<NGBLK, 256, 0, stream>>>(rowptr, csr_src, hsb, dis, b2, out);
}

// Round 9
// 239.774 us; speedup vs baseline: 1.8412x; 1.0510x over previous
//
#include <hip/hip_runtime.h>

#define N_NODES 100000
#define E_EDGES 1600000
#define IN_F    128
#define HID_F   64
#define OUT_F   64
#define BN_EPS  1e-5f
#define NBUK    391    // ceil(N/256) coarse buckets (256 nodes each)
#define CHUNK   6250   // E / 256 blocks
#define NGBLK   3125   // N/32 gather blocks (8 groups x 4 nodes, 64 threads)
#define NMBLK   1563   // ceil(N/64) gemm blocks

typedef __bf16 bf16x8 __attribute__((ext_vector_type(8)));
typedef float  f32x4  __attribute__((ext_vector_type(4)));

// bf16 helpers ---------------------------------------------------------------
__device__ __forceinline__ float bflo(unsigned int u) { return __uint_as_float(u << 16); }
__device__ __forceinline__ float bfhi(unsigned int u) { return __uint_as_float(u & 0xFFFF0000u); }
__device__ __forceinline__ unsigned int pack2bf(float a, float b) {
    unsigned int ua = __float_as_uint(a), ub = __float_as_uint(b);
    ua = (ua + 0x7fffu + ((ua >> 16) & 1u)) >> 16;          // RNE
    ub = (ub + 0x7fffu + ((ub >> 16) & 1u)) >> 16;
    return ua | (ub << 16);
}
__device__ __forceinline__ unsigned short bf1(float a) {
    unsigned int ua = __float_as_uint(a);
    return (unsigned short)((ua + 0x7fffu + ((ua >> 16) & 1u)) >> 16);
}
#define ADD8(A, u)                                           \
    do {                                                     \
        A[0] += bflo((u).x); A[1] += bfhi((u).x);            \
        A[2] += bflo((u).y); A[3] += bfhi((u).y);            \
        A[4] += bflo((u).z); A[5] += bfhi((u).z);            \
        A[6] += bflo((u).w); A[7] += bfhi((u).w);            \
    } while (0)

// ---------------------------------------------------------------------------
// 1. coarse histogram, non-atomic output: histbuf[block][391]
__global__ __launch_bounds__(512) void k_chist(const int* __restrict__ dstv,
                                               int* __restrict__ histbuf) {
    __shared__ int h[NBUK];
    const int tid = threadIdx.x;
    const int e0 = blockIdx.x * CHUNK;
    for (int b = tid; b < NBUK; b += 512) h[b] = 0;
    __syncthreads();
    for (int t = tid; t < CHUNK; t += 512)
        atomicAdd(&h[dstv[e0 + t] >> 8], 1);
    __syncthreads();
    for (int b = tid; b < NBUK; b += 512)
        histbuf[blockIdx.x * NBUK + b] = h[b];
}

// 2a. per-bucket exclusive scan along blocks: histbuf[b][bkt] -> running prefix,
//     bucket total -> btot[bkt]. One block per bucket.
__global__ __launch_bounds__(256) void k_cscan1(int* __restrict__ histbuf,
                                                int* __restrict__ btot) {
    __shared__ int sh[256];
    const int bkt = blockIdx.x, tid = threadIdx.x;
    int v = histbuf[tid * NBUK + bkt];
    sh[tid] = v;
    __syncthreads();
    for (int off = 1; off < 256; off <<= 1) {
        int t = (tid >= off) ? sh[tid - off] : 0;
        __syncthreads();
        sh[tid] += t;
        __syncthreads();
    }
    histbuf[tid * NBUK + bkt] = sh[tid] - v;   // exclusive prefix within bucket
    if (tid == 255) btot[bkt] = sh[255];
}

// 2b. exclusive scan of bucket totals -> coff
__global__ __launch_bounds__(512) void k_cscan2(const int* __restrict__ btot,
                                                int* __restrict__ coff) {
    __shared__ int sh[512];
    const int tid = threadIdx.x;
    int v = (tid < NBUK) ? btot[tid] : 0;
    sh[tid] = v;
    __syncthreads();
    for (int off = 1; off < 512; off <<= 1) {
        int t = (tid >= off) ? sh[tid - off] : 0;
        __syncthreads();
        sh[tid] += t;
        __syncthreads();
    }
    if (tid < NBUK) coff[tid] = sh[tid] - v;
    if (tid == 0) coff[NBUK] = E_EDGES;
}

// 3. bucket scatter (single pass): cursors preloaded from histbuf+coff.
__global__ __launch_bounds__(512) void k_bucket(const int* __restrict__ srcv,
                                                const int* __restrict__ dstv,
                                                const int* __restrict__ histbuf,
                                                const int* __restrict__ coff,
                                                unsigned int* __restrict__ aux) {
    __shared__ int cur[NBUK];                  // 1.6 KB
    const int tid = threadIdx.x;
    const int e0 = blockIdx.x * CHUNK;
    for (int i = tid; i < NBUK; i += 512)
        cur[i] = histbuf[blockIdx.x * NBUK + i] + coff[i];
    __syncthreads();
    for (int t = tid; t < CHUNK; t += 512) {
        int d = dstv[e0 + t];
        int s = srcv[e0 + t];
        int pos = atomicAdd(&cur[d >> 8], 1);
        aux[pos] = ((unsigned int)s << 8) | (unsigned int)(d & 255);
    }
}

// 4. per-bucket: per-node counts (LDS) -> rowptr + dis, then fine CSR placement.
__global__ __launch_bounds__(256) void k_csrnode(const int* __restrict__ coff,
                                                 const unsigned int* __restrict__ aux,
                                                 int* __restrict__ rowptr,
                                                 float* __restrict__ dis,
                                                 int* __restrict__ csr_src) {
    __shared__ int c0[256], sc[256], cur[256];
    const int tid = threadIdx.x;
    const int n0 = blockIdx.x * 256;
    const int nn = min(256, N_NODES - n0);
    const int estart = coff[blockIdx.x];
    const int eend   = coff[blockIdx.x + 1];
    c0[tid] = 0;
    __syncthreads();
    for (int e = estart + tid; e < eend; e += 256)
        atomicAdd(&c0[aux[e] & 255], 1);
    __syncthreads();
    int v = c0[tid];
    sc[tid] = v;
    __syncthreads();
    for (int off = 1; off < 256; off <<= 1) {
        int t = (tid >= off) ? sc[tid - off] : 0;
        __syncthreads();
        sc[tid] += t;
        __syncthreads();
    }
    int excl = sc[tid] - v;
    if (tid < nn) {
        int p = estart + excl;
        rowptr[n0 + tid] = p;
        cur[tid] = p;
        dis[n0 + tid] = rsqrtf((float)v + 1.0f);
    }
    if (blockIdx.x == NBUK - 1 && tid == 0) rowptr[N_NODES] = E_EDGES;
    __syncthreads();
    for (int e = estart + tid; e < eend; e += 256) {
        unsigned int u = aux[e];
        int pos = atomicAdd(&cur[u & 255], 1);
        csr_src[pos] = (int)(u >> 8);
    }
}

// ---------------------------------------------------------------------------
// 5. MFMA: hs1 = bf16( dis * (x @ W1) ); 64-row tile, 4 waves, 16x16x32 bf16.
__global__ __launch_bounds__(256) void k_gemm1(const float* __restrict__ x,
                                               const float* __restrict__ W1,
                                               const float* __restrict__ dis,
                                               unsigned short* __restrict__ hs1) {
    __shared__ unsigned short Asb[64 * 136];   // 17408 B
    __shared__ unsigned short Btb[64 * 136];   // 17408 B (Bt[n][k])
    __shared__ unsigned short Cc[64 * 72];     // 9216 B
    __shared__ float disS[64];
    const int tid = threadIdx.x;
    const int r0 = blockIdx.x * 64;

    if (tid < 64) disS[tid] = (r0 + tid < N_NODES) ? dis[r0 + tid] : 0.f;

    const float4* x4 = (const float4*)x;
#pragma unroll
    for (int p = 0; p < 4; ++p) {
        int idx8 = p * 256 + tid;
        int row = idx8 >> 4, c8 = idx8 & 15;
        float4 v0 = make_float4(0.f, 0.f, 0.f, 0.f), v1 = v0;
        if (r0 + row < N_NODES) {
            v0 = x4[(size_t)(r0 + row) * 32 + c8 * 2];
            v1 = x4[(size_t)(r0 + row) * 32 + c8 * 2 + 1];
        }
        uint4 u;
        u.x = pack2bf(v0.x, v0.y); u.y = pack2bf(v0.z, v0.w);
        u.z = pack2bf(v1.x, v1.y); u.w = pack2bf(v1.z, v1.w);
        *(uint4*)&Asb[row * 136 + c8 * 8] = u;
    }
    for (int idx = tid; idx < IN_F * HID_F; idx += 256) {
        int k = idx >> 6, n = idx & 63;
        Btb[n * 136 + k] = bf1(W1[idx]);
    }
    __syncthreads();

    const int wv = tid >> 6, lane = tid & 63;
    const int m = lane & 15, quad = lane >> 4;
    const int arow = wv * 16 + m;
    f32x4 acc[4] = {};
#pragma unroll
    for (int ks = 0; ks < 4; ++ks) {
        int k0 = ks * 32 + quad * 8;
        bf16x8 af = *(const bf16x8*)&Asb[arow * 136 + k0];
#pragma unroll
        for (int c = 0; c < 4; ++c) {
            bf16x8 bfr = *(const bf16x8*)&Btb[(c * 16 + m) * 136 + k0];
            acc[c] = __builtin_amdgcn_mfma_f32_16x16x32_bf16(af, bfr, acc[c], 0, 0, 0);
        }
    }
#pragma unroll
    for (int c = 0; c < 4; ++c)
#pragma unroll
        for (int r = 0; r < 4; ++r) {
            int rl = wv * 16 + quad * 4 + r;
            Cc[rl * 72 + c * 16 + m] = bf1(acc[c][r] * disS[rl]);
        }
    __syncthreads();
#pragma unroll
    for (int p = 0; p < 2; ++p) {
        int idx = p * 256 + tid;
        int row = idx >> 3, c8 = idx & 7;
        if (r0 + row < N_NODES)
            *(uint4*)&hs1[(size_t)(r0 + row) * 64 + c8 * 8] = *(uint4*)&Cc[row * 72 + c8 * 8];
    }
}

// ---------------------------------------------------------------------------
// 6. gather conv1: 64-thread blocks, 8 groups x 4 sequential nodes.
//    Variance smoothing: group work = sum of 4 Poisson degrees.
__global__ __launch_bounds__(64) void k_gather1(const int* __restrict__ rowptr,
                                                const int* __restrict__ csr_src,
                                                const unsigned short* __restrict__ hsb,
                                                const float* __restrict__ dis,
                                                const float* __restrict__ b1,
                                                unsigned short* __restrict__ aggb,
                                                float* __restrict__ partials) {
    const int tid = threadIdx.x;
    const int g = tid >> 3, q = tid & 7;
    const uint4* __restrict__ hs16 = (const uint4*)hsb;   // row = 8 uint4
    const float4 blo = ((const float4*)b1)[q * 2];
    const float4 bhi = ((const float4*)b1)[q * 2 + 1];

    float bsA[4] = {}, bsB[4] = {}, bqA[4] = {}, bqB[4] = {};

#pragma unroll
    for (int jj = 0; jj < 4; ++jj) {
        const int n = blockIdx.x * 32 + jj * 8 + g;
        const int start = rowptr[n], end = rowptr[n + 1];
        float A0[8] = {}, A1[8] = {}, A2[8] = {}, A3[8] = {};
        {   // self term
            uint4 u = hs16[(size_t)n * 8 + q];
            ADD8(A0, u);
        }
        int i = start;
        for (; i + 7 < end; i += 8) {
            int s0 = csr_src[i + 0], s1 = csr_src[i + 1];
            int s2 = csr_src[i + 2], s3 = csr_src[i + 3];
            int s4 = csr_src[i + 4], s5 = csr_src[i + 5];
            int s6 = csr_src[i + 6], s7 = csr_src[i + 7];
            uint4 u0 = hs16[(size_t)s0 * 8 + q];
            uint4 u1 = hs16[(size_t)s1 * 8 + q];
            uint4 u2 = hs16[(size_t)s2 * 8 + q];
            uint4 u3 = hs16[(size_t)s3 * 8 + q];
            uint4 u4 = hs16[(size_t)s4 * 8 + q];
            uint4 u5 = hs16[(size_t)s5 * 8 + q];
            uint4 u6 = hs16[(size_t)s6 * 8 + q];
            uint4 u7 = hs16[(size_t)s7 * 8 + q];
            ADD8(A0, u0); ADD8(A1, u1); ADD8(A2, u2); ADD8(A3, u3);
            ADD8(A0, u4); ADD8(A1, u5); ADD8(A2, u6); ADD8(A3, u7);
        }
        if (i + 3 < end) {
            int s0 = csr_src[i + 0], s1 = csr_src[i + 1];
            int s2 = csr_src[i + 2], s3 = csr_src[i + 3];
            uint4 u0 = hs16[(size_t)s0 * 8 + q];
            uint4 u1 = hs16[(size_t)s1 * 8 + q];
            uint4 u2 = hs16[(size_t)s2 * 8 + q];
            uint4 u3 = hs16[(size_t)s3 * 8 + q];
            ADD8(A0, u0); ADD8(A1, u1); ADD8(A2, u2); ADD8(A3, u3);
            i += 4;
        }
        for (; i < end; ++i) {
            uint4 u = hs16[(size_t)csr_src[i] * 8 + q];
            ADD8(A0, u);
        }
        const float d = dis[n];
        float o[8];
        o[0] = fmaf(d, A0[0] + A1[0] + A2[0] + A3[0], blo.x);
        o[1] = fmaf(d, A0[1] + A1[1] + A2[1] + A3[1], blo.y);
        o[2] = fmaf(d, A0[2] + A1[2] + A2[2] + A3[2], blo.z);
        o[3] = fmaf(d, A0[3] + A1[3] + A2[3] + A3[3], blo.w);
        o[4] = fmaf(d, A0[4] + A1[4] + A2[4] + A3[4], bhi.x);
        o[5] = fmaf(d, A0[5] + A1[5] + A2[5] + A3[5], bhi.y);
        o[6] = fmaf(d, A0[6] + A1[6] + A2[6] + A3[6], bhi.z);
        o[7] = fmaf(d, A0[7] + A1[7] + A2[7] + A3[7], bhi.w);
        uint4 ob;
        ob.x = pack2bf(o[0], o[1]); ob.y = pack2bf(o[2], o[3]);
        ob.z = pack2bf(o[4], o[5]); ob.w = pack2bf(o[6], o[7]);
        ((uint4*)aggb)[(size_t)n * 8 + q] = ob;
#pragma unroll
        for (int k = 0; k < 4; ++k) {
            bsA[k] += o[k];     bsB[k] += o[4 + k];
            bqA[k] = fmaf(o[k], o[k], bqA[k]);
            bqB[k] = fmaf(o[4 + k], o[4 + k], bqB[k]);
        }
    }

    // per-block BN partials over the 32 nodes (64 threads)
    __shared__ float4 redA[64], redB[64];
    redA[tid] = make_float4(bsA[0], bsA[1], bsA[2], bsA[3]);
    redB[tid] = make_float4(bsB[0], bsB[1], bsB[2], bsB[3]);
    __syncthreads();
    for (int s = 32; s >= 8; s >>= 1) {
        if (tid < s) {
            redA[tid].x += redA[tid + s].x; redA[tid].y += redA[tid + s].y;
            redA[tid].z += redA[tid + s].z; redA[tid].w += redA[tid + s].w;
            redB[tid].x += redB[tid + s].x; redB[tid].y += redB[tid + s].y;
            redB[tid].z += redB[tid + s].z; redB[tid].w += redB[tid + s].w;
        }
        __syncthreads();
    }
    float4* pr = (float4*)(partials + (size_t)blockIdx.x * 128);
    if (tid < 8) { pr[tid * 2] = redA[tid]; pr[tid * 2 + 1] = redB[tid]; }
    __syncthreads();
    redA[tid] = make_float4(bqA[0], bqA[1], bqA[2], bqA[3]);
    redB[tid] = make_float4(bqB[0], bqB[1], bqB[2], bqB[3]);
    __syncthreads();
    for (int s = 32; s >= 8; s >>= 1) {
        if (tid < s) {
            redA[tid].x += redA[tid + s].x; redA[tid].y += redA[tid + s].y;
            redA[tid].z += redA[tid + s].z; redA[tid].w += redA[tid + s].w;
            redB[tid].x += redB[tid + s].x; redB[tid].y += redB[tid + s].y;
            redB[tid].z += redB[tid + s].z; redB[tid].w += redB[tid + s].w;
        }
        __syncthreads();
    }
    if (tid < 8) { pr[16 + tid * 2] = redA[tid]; pr[16 + tid * 2 + 1] = redB[tid]; }
}

// 6b. reduce partials[NGBLK][128] -> bnstats[128]; block = column, no atomics.
__global__ __launch_bounds__(256) void k_bnfinal(const float* __restrict__ partials,
                                                 float* __restrict__ bnstats) {
    const int c = blockIdx.x;          // 0..127
    const int tid = threadIdx.x;
    float s = 0.f;
    for (int r = tid; r < NGBLK; r += 256)
        s += partials[(size_t)r * 128 + c];
    __shared__ float sh[256];
    sh[tid] = s;
    __syncthreads();
    for (int st = 128; st > 0; st >>= 1) {
        if (tid < st) sh[tid] += sh[tid + st];
        __syncthreads();
    }
    if (tid == 0) bnstats[c] = sh[0];
}

// ---------------------------------------------------------------------------
// 7. MFMA: hs2 = bf16( dis * (relu(BN(agg_bf16)) @ W2) ); K=64.
__global__ __launch_bounds__(256) void k_gemm2(const unsigned short* __restrict__ aggb,
                                               const float* __restrict__ W2,
                                               const float* __restrict__ dis,
                                               const float* __restrict__ bnw,
                                               const float* __restrict__ bnb,
                                               const float* __restrict__ bnstats,
                                               unsigned short* __restrict__ hs2) {
    __shared__ unsigned short Ab[64 * 72];     // 9216 B
    __shared__ unsigned short Bt2[64 * 72];    // 9216 B
    __shared__ unsigned short Cc[64 * 72];     // 9216 B
    __shared__ float scale_s[64], shift_s[64], disS[64];
    const int tid = threadIdx.x;
    const int r0 = blockIdx.x * 64;

    if (tid < 64) {
        const float invN = 1.0f / (float)N_NODES;
        float mean = bnstats[tid] * invN;
        float var  = bnstats[64 + tid] * invN - mean * mean;
        float sc   = bnw[tid] * rsqrtf(var + BN_EPS);
        scale_s[tid] = sc;
        shift_s[tid] = fmaf(-mean, sc, bnb[tid]);
        disS[tid] = (r0 + tid < N_NODES) ? dis[r0 + tid] : 0.f;
    }
    for (int idx = tid; idx < HID_F * OUT_F; idx += 256) {
        int k = idx >> 6, n = idx & 63;
        Bt2[n * 72 + k] = bf1(W2[idx]);
    }
    __syncthreads();   // scale_s/shift_s ready before A-stage uses them

    const uint4* a16 = (const uint4*)aggb;     // row = 8 uint4 (64 bf16)
#pragma unroll
    for (int p = 0; p < 2; ++p) {
        int idx = p * 256 + tid;               // 512 uint4 total
        int row = idx >> 3, q = idx & 7;
        uint4 u = make_uint4(0, 0, 0, 0);
        if (r0 + row < N_NODES) u = a16[(size_t)(r0 + row) * 8 + q];
        int k0 = q * 8;
        float v[8];
        v[0] = bflo(u.x); v[1] = bfhi(u.x); v[2] = bflo(u.y); v[3] = bfhi(u.y);
        v[4] = bflo(u.z); v[5] = bfhi(u.z); v[6] = bflo(u.w); v[7] = bfhi(u.w);
        uint4 o;
        float w0 = fmaxf(fmaf(v[0], scale_s[k0 + 0], shift_s[k0 + 0]), 0.f);
        float w1 = fmaxf(fmaf(v[1], scale_s[k0 + 1], shift_s[k0 + 1]), 0.f);
        float w2 = fmaxf(fmaf(v[2], scale_s[k0 + 2], shift_s[k0 + 2]), 0.f);
        float w3 = fmaxf(fmaf(v[3], scale_s[k0 + 3], shift_s[k0 + 3]), 0.f);
        float w4 = fmaxf(fmaf(v[4], scale_s[k0 + 4], shift_s[k0 + 4]), 0.f);
        float w5 = fmaxf(fmaf(v[5], scale_s[k0 + 5], shift_s[k0 + 5]), 0.f);
        float w6 = fmaxf(fmaf(v[6], scale_s[k0 + 6], shift_s[k0 + 6]), 0.f);
        float w7 = fmaxf(fmaf(v[7], scale_s[k0 + 7], shift_s[k0 + 7]), 0.f);
        o.x = pack2bf(w0, w1); o.y = pack2bf(w2, w3);
        o.z = pack2bf(w4, w5); o.w = pack2bf(w6, w7);
        *(uint4*)&Ab[row * 72 + q * 8] = o;
    }
    __syncthreads();

    const int wv = tid >> 6, lane = tid & 63;
    const int m = lane & 15, quad = lane >> 4;
    const int arow = wv * 16 + m;
    f32x4 acc[4] = {};
#pragma unroll
    for (int ks = 0; ks < 2; ++ks) {
        int k0 = ks * 32 + quad * 8;
        bf16x8 af = *(const bf16x8*)&Ab[arow * 72 + k0];
#pragma unroll
        for (int c = 0; c < 4; ++c) {
            bf16x8 bfr = *(const bf16x8*)&Bt2[(c * 16 + m) * 72 + k0];
            acc[c] = __builtin_amdgcn_mfma_f32_16x16x32_bf16(af, bfr, acc[c], 0, 0, 0);
        }
    }
#pragma unroll
    for (int c = 0; c < 4; ++c)
#pragma unroll
        for (int r = 0; r < 4; ++r) {
            int rl = wv * 16 + quad * 4 + r;
            Cc[rl * 72 + c * 16 + m] = bf1(acc[c][r] * disS[rl]);
        }
    __syncthreads();
#pragma unroll
    for (int p = 0; p < 2; ++p) {
        int idx = p * 256 + tid;
        int row = idx >> 3, c8 = idx & 7;
        if (r0 + row < N_NODES)
            *(uint4*)&hs2[(size_t)(r0 + row) * 64 + c8 * 8] = *(uint4*)&Cc[row * 72 + c8 * 8];
    }
}

// ---------------------------------------------------------------------------
// 8. gather conv2: same 4-node-per-group structure, fp32 out.
__global__ __launch_bounds__(64) void k_gather2(const int* __restrict__ rowptr,
                                                const int* __restrict__ csr_src,
                                                const unsigned short* __restrict__ hsb,
                                                const float* __restrict__ dis,
                                                const float* __restrict__ b2,
                                                float* __restrict__ out) {
    const int tid = threadIdx.x;
    const int g = tid >> 3, q = tid & 7;
    const uint4* __restrict__ hs16 = (const uint4*)hsb;
    const float4 blo = ((const float4*)b2)[q * 2];
    const float4 bhi = ((const float4*)b2)[q * 2 + 1];

#pragma unroll
    for (int jj = 0; jj < 4; ++jj) {
        const int n = blockIdx.x * 32 + jj * 8 + g;
        const int start = rowptr[n], end = rowptr[n + 1];
        float A0[8] = {}, A1[8] = {}, A2[8] = {}, A3[8] = {};
        {
            uint4 u = hs16[(size_t)n * 8 + q];
            ADD8(A0, u);
        }
        int i = start;
        for (; i + 7 < end; i += 8) {
            int s0 = csr_src[i + 0], s1 = csr_src[i + 1];
            int s2 = csr_src[i + 2], s3 = csr_src[i + 3];
            int s4 = csr_src[i + 4], s5 = csr_src[i + 5];
            int s6 = csr_src[i + 6], s7 = csr_src[i + 7];
            uint4 u0 = hs16[(size_t)s0 * 8 + q];
            uint4 u1 = hs16[(size_t)s1 * 8 + q];
            uint4 u2 = hs16[(size_t)s2 * 8 + q];
            uint4 u3 = hs16[(size_t)s3 * 8 + q];
            uint4 u4 = hs16[(size_t)s4 * 8 + q];
            uint4 u5 = hs16[(size_t)s5 * 8 + q];
            uint4 u6 = hs16[(size_t)s6 * 8 + q];
            uint4 u7 = hs16[(size_t)s7 * 8 + q];
            ADD8(A0, u0); ADD8(A1, u1); ADD8(A2, u2); ADD8(A3, u3);
            ADD8(A0, u4); ADD8(A1, u5); ADD8(A2, u6); ADD8(A3, u7);
        }
        if (i + 3 < end) {
            int s0 = csr_src[i + 0], s1 = csr_src[i + 1];
            int s2 = csr_src[i + 2], s3 = csr_src[i + 3];
            uint4 u0 = hs16[(size_t)s0 * 8 + q];
            uint4 u1 = hs16[(size_t)s1 * 8 + q];
            uint4 u2 = hs16[(size_t)s2 * 8 + q];
            uint4 u3 = hs16[(size_t)s3 * 8 + q];
            ADD8(A0, u0); ADD8(A1, u1); ADD8(A2, u2); ADD8(A3, u3);
            i += 4;
        }
        for (; i < end; ++i) {
            uint4 u = hs16[(size_t)csr_src[i] * 8 + q];
            ADD8(A0, u);
        }
        const float d = dis[n];
        float4 o0, o1;
        o0.x = fmaf(d, A0[0] + A1[0] + A2[0] + A3[0], blo.x);
        o0.y = fmaf(d, A0[1] + A1[1] + A2[1] + A3[1], blo.y);
        o0.z = fmaf(d, A0[2] + A1[2] + A2[2] + A3[2], blo.z);
        o0.w = fmaf(d, A0[3] + A1[3] + A2[3] + A3[3], blo.w);
        o1.x = fmaf(d, A0[4] + A1[4] + A2[4] + A3[4], bhi.x);
        o1.y = fmaf(d, A0[5] + A1[5] + A2[5] + A3[5], bhi.y);
        o1.z = fmaf(d, A0[6] + A1[6] + A2[6] + A3[6], bhi.z);
        o1.w = fmaf(d, A0[7] + A1[7] + A2[7] + A3[7], bhi.w);
        float4* op = (float4*)(out + (size_t)n * OUT_F + q * 8);
        op[0] = o0;
        op[1] = o1;
    }
}

// ---------------------------------------------------------------------------
extern "C" void kernel_launch(void* const* d_in, const int* in_sizes, int n_in,
                              void* d_out, int out_size, void* d_ws, size_t ws_size,
                              hipStream_t stream) {
    const float* x   = (const float*)d_in[0];
    const int*   ei  = (const int*)d_in[1];
    const float* W1  = (const float*)d_in[2];
    const float* b1  = (const float*)d_in[3];
    const float* bnw = (const float*)d_in[4];
    const float* bnb = (const float*)d_in[5];
    const float* W2  = (const float*)d_in[6];
    const float* b2  = (const float*)d_in[7];
    float* out = (float*)d_out;

    // workspace layout (floats, 16B-aligned segments):
    float* ws = (float*)d_ws;
    float*        dis     = ws;                               // 100352
    int*          rowptr  = (int*)(ws + 100352);              // 100608 (N+1 used)
    int*          coff    = (int*)(ws + 200960);              // 512 (NBUK+1 used)
    int*          btot    = (int*)(ws + 201472);              // 512
    float*        bnstats = ws + 201984;                      // 128
    int*          histbuf = (int*)(ws + 202112);              // 256*391 -> 100352
    int*          csr_src = (int*)(ws + 302464);              // 1.6M
    float*        bufA    = ws + 1902464;                     // N*64 fp32 region
    float*        bufB    = bufA + (size_t)N_NODES * HID_F;   // N*64 region
    unsigned int*   aux  = (unsigned int*)bufA;    // CSR-build scratch, dead before gemm1
    unsigned short* hsb  = (unsigned short*)bufA;  // bf16 hs1, then bf16 hs2 (12.8 MB)
    unsigned short* aggb = (unsigned short*)bufB;  // bf16 agg (12.8 MB)
    float* partials = out;                         // NGBLK*128 floats, dead until gather2

    const int* srcv = ei;
    const int* dstv = ei + E_EDGES;

    k_chist  <<<256, 512, 0, stream>>>(dstv, histbuf);
    k_cscan1 <<<NBUK, 256, 0, stream>>>(histbuf, btot);
    k_cscan2 <<<1, 512, 0, stream>>>(btot, coff);
    k_bucket <<<256, 512, 0, stream>>>(srcv, dstv, histbuf, coff, aux);
    k_csrnode<<<NBUK, 256, 0, stream>>>(coff, aux, rowptr, dis, csr_src);

    k_gemm1  <<<NMBLK, 256, 0, stream>>>(x, W1, dis, hsb);
    k_gather1<<<NGBLK, 64, 0, stream>>>(rowptr, csr_src, hsb, dis, b1, aggb, partials);
    k_bnfinal<<<128, 256, 0, stream>>>(partials, bnstats);
    k_gemm2  <<<NMBLK, 256, 0, stream>>>(aggb, W2, dis, bnw, bnb, bnstats, hsb);
    k_gather2<<<NGBLK, 64, 0, stream>>>(rowptr, csr_src, hsb, dis, b2, out);
}